// Round 21
// baseline (15418.375 us; speedup 1.0000x reference)
//
#include <hip/hip_runtime.h>
#include <hip/hip_bf16.h>

typedef __attribute__((ext_vector_type(8))) short short8;
typedef __attribute__((ext_vector_type(4))) float f32x4;
typedef __attribute__((ext_vector_type(4))) unsigned uint4v;
typedef unsigned long long u64;

#define T_STEPS 512
#define BATCH 64
#define HID 1024
#define DIN 512
#define NBLOCKS 128
#define NTHREADS 1024

// ---- workspace layout (bytes) ----
#define WS_GRP 0                // 8 group counters (16 blocks each), 128B stride
#define WS_H0 4096              // 2 * 131072 (double-buffered h0, bf16 frag tiles)
#define WS_H1 (4096 + 262144)   // 2 * 131072
#define WS_XB (1u << 20)        // x cast to bf16 frag tiles: 32 MB
#define HBUF 131072

#define MFMA __builtin_amdgcn_mfma_f32_16x16x32_bf16

__device__ __forceinline__ short bf16r(float x) {
  unsigned u = __builtin_bit_cast(unsigned, x);
  u += 0x7FFFu + ((u >> 16) & 1u);   // round-to-nearest-even
  return (short)(u >> 16);
}

__device__ __forceinline__ float sigf(float x) {
  return 1.0f / (1.0f + __expf(-x));
}
__device__ __forceinline__ float tanh_(float x) {
  return 2.0f * sigf(2.0f * x) - 1.0f;
}

__device__ __forceinline__ short8 pack8(const float* p) {
  float4 a = *(const float4*)p;
  float4 c = *(const float4*)(p + 4);
  short8 v;
  v[0] = bf16r(a.x); v[1] = bf16r(a.y); v[2] = bf16r(a.z); v[3] = bf16r(a.w);
  v[4] = bf16r(c.x); v[5] = bf16r(c.y); v[6] = bf16r(c.z); v[7] = bf16r(c.w);
  return v;
}

// MALL-coherent 16B fragment load (R14-proven): ONE buffer_load_dwordx4 with
// CPol SC0|SC1 = 0x11 -> bypasses L1/L2, reads the MALL coherence point.
// Compiler-tracked (auto vmcnt). Fence-free protocol proven R7-R18.
__device__ __forceinline__ short8 ld_frag16(const void* base, int voff) {
  __amdgpu_buffer_rsrc_t rsrc = __builtin_amdgcn_make_buffer_rsrc(
      const_cast<void*>(base), (short)0, 0xFFFFFFFFu, 0x00020000u);
  uint4v f = __builtin_amdgcn_raw_buffer_load_b128(rsrc, voff, 0, 0x11);
  return __builtin_bit_cast(short8, f);
}

// Direct-poll barrier wait: poller wave's lanes 0-7 read the 8 group
// counters DIRECTLY (no root hop — one less MALL RT on the signal chain),
// exit via __all; lane 0 broadcasts through LDS. Other waves spin on LDS.
__device__ __forceinline__ void wait_gen(unsigned* grp, unsigned* gen_lds,
                                         unsigned s, int tid) {
  if ((tid >> 6) == 15) {
    const int l = tid & 63;
    const unsigned tgt = 16u * s;   // 16 blocks increment each group counter
    int g = 0;
    for (;;) {
      unsigned v = (l < 8) ? __hip_atomic_load(&grp[l * 32], __ATOMIC_RELAXED,
                                               __HIP_MEMORY_SCOPE_AGENT) : tgt;
      if (__all(v >= tgt)) break;
      __builtin_amdgcn_s_sleep(1);
      if (++g > (1 << 16)) break;   // anti-hang bail (legit waits are ~µs)
    }
    if (l == 0)
      __hip_atomic_store(gen_lds, s, __ATOMIC_RELEASE, __HIP_MEMORY_SCOPE_WORKGROUP);
  }
  int g = 0;
  while (__hip_atomic_load(gen_lds, __ATOMIC_ACQUIRE, __HIP_MEMORY_SCOPE_WORKGROUP) < s) {
    __builtin_amdgcn_s_sleep(1);
    if (++g > (1 << 17)) break;
  }
}

// Cast x [64][512][512] fp32 -> bf16 MFMA A-fragment tiles:
// xb[t][m=b/16][kt=k/32] tile of 1024B; within tile: lane=(b&15)+16*((k>>3)&3), elem=k&7
__global__ void cast_x_kernel(const float* __restrict__ x, unsigned char* __restrict__ ws) {
  unsigned char* xb = ws + WS_XB;
  int idx = blockIdx.x * blockDim.x + threadIdx.x;   // 0..262143
  for (int c = idx; c < 64 * 512 * 64; c += 262144) {
    const int b = c >> 15;
    const int t = (c >> 6) & 511;
    const int kc = c & 63;
    const float* src = x + (((b << 9) + t) << 9) + (kc << 3);
    short8 v = pack8(src);
    const int kt = kc >> 2;
    const int ln = (b & 15) + ((kc & 3) << 4);
    unsigned char* dst = xb + (((t << 2) + (b >> 4)) * 16 + kt) * 1024 + ln * 16;
    *(short8*)dst = v;
  }
}

// R21 = R19/R20 structure with backend-native occupancy attributes instead of
// __launch_bounds__ (which demonstrably did not reach the register-budget
// calc: R19 (1024,1) and R20 (1024,4) produced IDENTICAL 64-VGPR spilled
// code, FETCH 26.7 GB). amdgpu_waves_per_eu(4,4) pins 4 waves/EU = 1 block/CU
// for this 16-wave block -> VGPR cap 2048/4 = 512 >= ~206 live set.
// Structure: 128 blocks x 16 waves, 2 M-groups x 64 N-groups (16 cols each);
// each block reads ONLY its M-half of h -> device bypass ops 16384 (half of
// R14/R18 — the proven scaling knob). 16-way K-split keeps per-wave weights
// at 28 frags = 112 VGPRs.
__global__ __attribute__((amdgpu_flat_work_group_size(1024, 1024)))
__attribute__((amdgpu_waves_per_eu(4, 4))) void lstm_main(
    const float* __restrict__ Wih0, const float* __restrict__ Whh0,
    const float* __restrict__ bih0, const float* __restrict__ bhh0,
    const float* __restrict__ Wih1, const float* __restrict__ Whh1,
    const float* __restrict__ bih1, const float* __restrict__ bhh1,
    float* __restrict__ out, unsigned char* __restrict__ ws)
{
  __shared__ float red[16][2][4][64][4];   // [wave][mm][gate][lane][reg] = 128 KB
  __shared__ unsigned gen_lds;

  const int tid = threadIdx.x;
  const int wid = tid >> 6;
  const int lane = tid & 63;
  const int blk = blockIdx.x;
  const int mg = blk >> 6;        // M-group: batch rows mg*32..mg*32+31
  const int ng = blk & 63;        // N-group: h columns ng*16..ng*16+15
  const int lane16 = lane * 16;

  unsigned* grp = (unsigned*)(ws + WS_GRP);
  unsigned char* h0b = ws + WS_H0;
  unsigned char* h1b = ws + WS_H1;
  const unsigned char* xb = ws + WS_XB;

  // ---------- persistent weight fragments (28 x short8 = 112 VGPRs) ----------
  // gate nt in 0..3, col = lane&15; weight row = nt*1024 + ng*16 + col.
  // Wave w (of 16): x-ktile {w}; h0-ktiles {2w,2w+1} (used for BOTH Whh0 and
  // Wih1); h1-ktiles {2w,2w+1} (Whh1).
  // wf: [0..3]=Wih0[nt] [4..11]=Whh0[i*4+nt] [12..19]=Wih1 [20..27]=Whh1
  short8 wf[28];
  {
    const int hi8 = (lane >> 4) << 3;
#pragma unroll
    for (int nt = 0; nt < 4; ++nt) {
      const int row = (nt << 10) + ng * 16 + (lane & 15);
      wf[nt] = pack8(Wih0 + row * DIN + wid * 32 + hi8);
#pragma unroll
      for (int i = 0; i < 2; ++i) {
        const int k = (2 * wid + i) * 32 + hi8;
        wf[4 + i * 4 + nt]  = pack8(Whh0 + row * HID + k);
        wf[12 + i * 4 + nt] = pack8(Wih1 + row * HID + k);
        wf[20 + i * 4 + nt] = pack8(Whh1 + row * HID + k);
      }
    }
  }

  // ---------- per-thread epilogue state (threads 0..511 only) ----------
  const int j = tid & 15;          // column within block
  const int bl = (tid >> 4) & 31;  // local batch row 0..31
  const int b = mg * 32 + bl;      // global batch row
  const int jg = ng * 16 + j;      // global h column
  const int m = bl >> 4;           // local Mtile 0..1
  const int r = bl & 15;           // row within tile
  const bool epi = (tid < 512);
  float bias0[4], bias1[4];
#pragma unroll
  for (int g = 0; g < 4; ++g) {
    bias0[g] = bih0[g * HID + jg] + bhh0[g * HID + jg];
    bias1[g] = bih1[g * HID + jg] + bhh1[g * HID + jg];
  }
  float c0 = 0.0f, c1 = 0.0f;
  // byte offset of h(b, jg) inside one parity buffer (frag-tile layout)
  const int hoff = ((b >> 4) * 32 + (jg >> 5)) * 1024 +
                   ((b & 15) + 16 * ((jg >> 3) & 3)) * 16 + (jg & 7) * 2;

  if (tid == 0) __hip_atomic_store(&gen_lds, 0u, __ATOMIC_RELAXED, __HIP_MEMORY_SCOPE_WORKGROUP);
  __syncthreads();

  // ---------- wavefront loop: interval s computes layer0(s) and layer1(s-1) ----------
  for (int s = 0; s <= T_STEPS; ++s) {
    const int p0 = s & 1;
    const bool doL0 = (s < T_STEPS);
    const bool doL1 = (s >= 1);
    const unsigned char* h0r = h0b + (p0 ^ 1) * HBUF;   // h0(s-1)  (zeros at s=0)
    const unsigned char* h1r = h1b + p0 * HBUF;         // h1(s-2)

    // x part first — no barrier dependency, overlaps the wait below
    f32x4 acc0[2][4];
    if (doL0) {
      const unsigned char* xs = xb + s * 65536;
#pragma unroll
      for (int mm = 0; mm < 2; ++mm) {
        short8 af = *(const short8*)(xs + (((mg * 2 + mm) * 16) + wid) * 1024 + lane16);
#pragma unroll
        for (int nt = 0; nt < 4; ++nt) {
          acc0[mm][nt] = (f32x4){0.f, 0.f, 0.f, 0.f};
          acc0[mm][nt] = MFMA(af, wf[nt], acc0[mm][nt], 0, 0, 0);
        }
      }
    }

    wait_gen(grp, &gen_lds, (unsigned)s, tid);   // h0(s-1)/h1(s-2) at MALL

    // h part: block reads ONLY its M-half; each h0 tile loaded once,
    // used for layer0 AND layer1. acc0 flushed per-mm; a1 held in regs.
    f32x4 a1[2][4];
#pragma unroll
    for (int mm = 0; mm < 2; ++mm) {
      const int tb = ((mg * 2 + mm) * 32 + 2 * wid) * 1024;
      short8 f0[2], f1[2];
      f0[0] = ld_frag16(h0r, tb + lane16);
      f0[1] = ld_frag16(h0r, tb + 1024 + lane16);
      if (doL1) {
        f1[0] = ld_frag16(h1r, tb + lane16);
        f1[1] = ld_frag16(h1r, tb + 1024 + lane16);
      }

      if (doL0) {
#pragma unroll
        for (int i = 0; i < 2; ++i)
#pragma unroll
          for (int nt = 0; nt < 4; ++nt)
            acc0[mm][nt] = MFMA(f0[i], wf[4 + i * 4 + nt], acc0[mm][nt], 0, 0, 0);
#pragma unroll
        for (int nt = 0; nt < 4; ++nt)
          *(f32x4*)(&red[wid][mm][nt][lane][0]) = acc0[mm][nt];   // flush
      }
#pragma unroll
      for (int nt = 0; nt < 4; ++nt) a1[mm][nt] = (f32x4){0.f, 0.f, 0.f, 0.f};
      if (doL1) {
#pragma unroll
        for (int i = 0; i < 2; ++i)
#pragma unroll
          for (int nt = 0; nt < 4; ++nt)
            a1[mm][nt] = MFMA(f0[i], wf[12 + i * 4 + nt], a1[mm][nt], 0, 0, 0);
#pragma unroll
        for (int i = 0; i < 2; ++i)
#pragma unroll
          for (int nt = 0; nt < 4; ++nt)
            a1[mm][nt] = MFMA(f1[i], wf[20 + i * 4 + nt], a1[mm][nt], 0, 0, 0);
      }
    }
    __syncthreads();   // L0 partials in red

    // ---------- phase A: layer0 reduce (16-way K-split) + epilogue ----------
    if (doL0 && epi) {
      float sg[4];
#pragma unroll
      for (int g = 0; g < 4; ++g) {
        const int ln = ((r >> 2) << 4) | j;
        const int rg = r & 3;
        float t = bias0[g];
#pragma unroll
        for (int w2 = 0; w2 < 16; ++w2) t += red[w2][m][g][ln][rg];
        sg[g] = t;
      }
      const float iv = sigf(sg[0]);
      const float fv = sigf(sg[1]);
      const float gv = tanh_(sg[2]);
      const float ov = sigf(sg[3]);
      c0 = fv * c0 + iv * gv;
      const float h0v = ov * tanh_(c0);
      // pack 2 adjacent columns' bf16 into one 4B bypass store (MALL-visible)
      unsigned hb = (unsigned)bf16r(h0v) & 0xFFFFu;
      unsigned nb = (unsigned)__shfl_down((int)hb, 1) & 0xFFFFu;
      if ((j & 1) == 0)
        __hip_atomic_store((unsigned*)(h0b + p0 * HBUF + hoff), hb | (nb << 16),
                           __ATOMIC_RELAXED, __HIP_MEMORY_SCOPE_AGENT);
    }
    __syncthreads();   // red consumed by phase A

    // ---------- phase B: flush a1, layer1 reduce + epilogue ----------
    if (doL1) {
#pragma unroll
      for (int mm = 0; mm < 2; ++mm)
#pragma unroll
        for (int nt = 0; nt < 4; ++nt)
          *(f32x4*)(&red[wid][mm][nt][lane][0]) = a1[mm][nt];
    }
    __syncthreads();   // L1 partials in red
    float outv = 0.0f;
    if (doL1 && epi) {
      float sg[4];
#pragma unroll
      for (int g = 0; g < 4; ++g) {
        const int ln = ((r >> 2) << 4) | j;
        const int rg = r & 3;
        float t = bias1[g];
#pragma unroll
        for (int w2 = 0; w2 < 16; ++w2) t += red[w2][m][g][ln][rg];
        sg[g] = t;
      }
      const float iv = sigf(sg[0]);
      const float fv = sigf(sg[1]);
      const float gv = tanh_(sg[2]);
      const float ov = sigf(sg[3]);
      c1 = fv * c1 + iv * gv;
      const float h1v = ov * tanh_(c1);
      outv = sigf(h1v);
      unsigned hb = (unsigned)bf16r(h1v) & 0xFFFFu;
      unsigned nb = (unsigned)__shfl_down((int)hb, 1) & 0xFFFFu;
      if ((j & 1) == 0)
        __hip_atomic_store((unsigned*)(h1b + (p0 ^ 1) * HBUF + hoff), hb | (nb << 16),
                           __ATOMIC_RELAXED, __HIP_MEMORY_SCOPE_AGENT);
    }

    // h stores acked at coherence point before block-wide signal
    asm volatile("s_waitcnt vmcnt(0)" ::: "memory");
    __syncthreads();   // red consumed, all waves' stores drained

    if (doL0 && tid == 0)
      __hip_atomic_fetch_add(&grp[(blk >> 4) * 32], 1u,
                             __ATOMIC_RELAXED, __HIP_MEMORY_SCOPE_AGENT);

    // out-store AFTER the signal — its HBM ack is off the critical chain
    if (doL1 && epi)
      __builtin_nontemporal_store(outv, &out[b * (T_STEPS * HID) + (s - 1) * HID + jg]);
  }
}

extern "C" void kernel_launch(void* const* d_in, const int* in_sizes, int n_in,
                              void* d_out, int out_size, void* d_ws, size_t ws_size,
                              hipStream_t stream) {
  const float* x    = (const float*)d_in[0];
  const float* Wih0 = (const float*)d_in[1];
  const float* Whh0 = (const float*)d_in[2];
  const float* bih0 = (const float*)d_in[3];
  const float* bhh0 = (const float*)d_in[4];
  const float* Wih1 = (const float*)d_in[5];
  const float* Whh1 = (const float*)d_in[6];
  const float* bih1 = (const float*)d_in[7];
  const float* bhh1 = (const float*)d_in[8];
  unsigned char* ws = (unsigned char*)d_ws;

  // zero barrier counters + h double-buffers (deterministic per call)
  (void)hipMemsetAsync(d_ws, 0, WS_XB, stream);
  hipLaunchKernelGGL(cast_x_kernel, dim3(1024), dim3(256), 0, stream, x, ws);
  hipLaunchKernelGGL(lstm_main, dim3(NBLOCKS), dim3(NTHREADS), 0, stream,
                     Wih0, Whh0, bih0, bhh0, Wih1, Whh1, bih1, bhh1,
                     (float*)d_out, ws);
}

// Round 22
// 3284.668 us; speedup vs baseline: 4.6940x; 4.6940x over previous
//
#include <hip/hip_runtime.h>
#include <hip/hip_bf16.h>

typedef __attribute__((ext_vector_type(8))) short short8;
typedef __attribute__((ext_vector_type(4))) float f32x4;
typedef __attribute__((ext_vector_type(4))) unsigned uint4v;
typedef unsigned long long u64;

#define T_STEPS 512
#define BATCH 64
#define HID 1024
#define DIN 512
#define NBLOCKS 256
#define NTHREADS 512

// ---- workspace layout (bytes) ----
#define WS_GRP 0                // 8 group counters (32 blocks each), 128B stride
#define WS_ROOT 2048            // root counter (1 word)
#define WS_H0 4096              // 2 * 131072 (double-buffered h0, bf16 frag tiles)
#define WS_H1 (4096 + 262144)   // 2 * 131072
#define WS_XB (1u << 20)        // x cast to bf16 frag tiles: 32 MB
#define HBUF 131072

#define MFMA __builtin_amdgcn_mfma_f32_16x16x32_bf16

__device__ __forceinline__ short bf16r(float x) {
  unsigned u = __builtin_bit_cast(unsigned, x);
  u += 0x7FFFu + ((u >> 16) & 1u);   // round-to-nearest-even
  return (short)(u >> 16);
}

__device__ __forceinline__ float sigf(float x) {
  return 1.0f / (1.0f + __expf(-x));
}
__device__ __forceinline__ float tanh_(float x) {
  return 2.0f * sigf(2.0f * x) - 1.0f;
}

__device__ __forceinline__ short8 pack8(const float* p) {
  float4 a = *(const float4*)p;
  float4 c = *(const float4*)(p + 4);
  short8 v;
  v[0] = bf16r(a.x); v[1] = bf16r(a.y); v[2] = bf16r(a.z); v[3] = bf16r(a.w);
  v[4] = bf16r(c.x); v[5] = bf16r(c.y); v[6] = bf16r(c.z); v[7] = bf16r(c.w);
  return v;
}

// MALL-coherent 16B fragment load (R14-proven): ONE buffer_load_dwordx4 with
// CPol SC0|SC1 = 0x11 -> bypasses L1/L2, reads the MALL coherence point.
// Compiler-tracked (auto vmcnt). Fence-free protocol proven R7-R18.
__device__ __forceinline__ short8 ld_frag16(const void* base, int voff) {
  __amdgpu_buffer_rsrc_t rsrc = __builtin_amdgcn_make_buffer_rsrc(
      const_cast<void*>(base), (short)0, 0xFFFFFFFFu, 0x00020000u);
  uint4v f = __builtin_amdgcn_raw_buffer_load_b128(rsrc, voff, 0, 0x11);
  return __builtin_bit_cast(short8, f);
}

// Barrier wait (R14-proven): one lane (tid 256) polls the root word with
// sleep backoff; broadcasts via an LDS generation word. All other waves spin
// on LDS only. No cache-maintenance ops anywhere (h moves via bypass).
__device__ __forceinline__ void wait_gen(unsigned* root, unsigned* gen_lds,
                                         unsigned s, int tid) {
  if (tid == 256) {
    const unsigned tgt = 8u * s;   // 8 groups increment root once per interval
    int g = 0;
    while (__hip_atomic_load(root, __ATOMIC_RELAXED, __HIP_MEMORY_SCOPE_AGENT) < tgt) {
      __builtin_amdgcn_s_sleep(2);
      if (++g > (1 << 13)) break;   // anti-hang bail (legit waits are ~µs)
    }
    __hip_atomic_store(gen_lds, s, __ATOMIC_RELEASE, __HIP_MEMORY_SCOPE_WORKGROUP);
  }
  int g = 0;
  while (__hip_atomic_load(gen_lds, __ATOMIC_ACQUIRE, __HIP_MEMORY_SCOPE_WORKGROUP) < s) {
    __builtin_amdgcn_s_sleep(1);
    if (++g > (1 << 17)) break;
  }
}

// Cast x [64][512][512] fp32 -> bf16 MFMA A-fragment tiles:
// xb[t][m=b/16][kt=k/32] tile of 1024B; within tile: lane=(b&15)+16*((k>>3)&3), elem=k&7
__global__ void cast_x_kernel(const float* __restrict__ x, unsigned char* __restrict__ ws) {
  unsigned char* xb = ws + WS_XB;
  int idx = blockIdx.x * blockDim.x + threadIdx.x;   // 0..262143
  for (int c = idx; c < 64 * 512 * 64; c += 262144) {
    const int b = c >> 15;
    const int t = (c >> 6) & 511;
    const int kc = c & 63;
    const float* src = x + (((b << 9) + t) << 9) + (kc << 3);
    short8 v = pack8(src);
    const int kt = kc >> 2;
    const int ln = (b & 15) + ((kc & 3) << 4);
    unsigned char* dst = xb + (((t << 2) + (b >> 4)) * 16 + kt) * 1024 + ln * 16;
    *(short8*)dst = v;
  }
}

// R22 = R18 restored (session best: 3286 us). 256 blocks = 2 M-groups x 128
// N-groups on all 256 CUs. Block (mg = blk>>7, ng = blk&127) owns batch rows
// [mg*32, mg*32+32) x gate-columns ng*8..ng*8+7 for BOTH layers. wf[28] =
// 112 VGPRs (proven no-spill at 512 threads); LDS 64 KB -> 1 block/CU.
// (The 16384-device-op variant needs 1024-thread blocks, which this
// toolchain compiles at 64 VGPRs with wf spilled — R19/R20/R21 all 15.4 ms.)
__global__ __launch_bounds__(NTHREADS, 1) void lstm_main(
    const float* __restrict__ Wih0, const float* __restrict__ Whh0,
    const float* __restrict__ bih0, const float* __restrict__ bhh0,
    const float* __restrict__ Wih1, const float* __restrict__ Whh1,
    const float* __restrict__ bih1, const float* __restrict__ bhh1,
    float* __restrict__ out, unsigned char* __restrict__ ws)
{
  __shared__ float red[8][2][2][64][4];    // layer0 partials [kwave][mm][nt][lane][reg], 32 KB
  __shared__ float red2[8][2][2][64][4];   // layer1 partials, 32 KB
  __shared__ unsigned gen_lds;

  const int tid = threadIdx.x;
  const int wid = tid >> 6;
  const int lane = tid & 63;
  const int blk = blockIdx.x;
  const int mg = blk >> 7;        // M-group: batch rows mg*32..mg*32+31
  const int ng = blk & 127;       // N-group: gate columns ng*8..ng*8+7
  const int lane16 = lane * 16;

  unsigned* grp = (unsigned*)(ws + WS_GRP);
  unsigned* root = (unsigned*)(ws + WS_ROOT);
  unsigned char* h0b = ws + WS_H0;
  unsigned char* h1b = ws + WS_H1;
  const unsigned char* xb = ws + WS_XB;

  // ---------- persistent weight fragments (28 x short8 = 112 VGPRs) ----------
  // Ntile n in 0..31: gate = n>>3, col = ng*8 + (n&7); weight row = gate*1024+col.
  // Wave w owns x-ktiles {2w,2w+1}; h0-ktiles {4w..4w+3} (used for BOTH
  // Whh0/layer0 and Wih1/layer1); h1-ktiles {4w..4w+3} (Whh1).
  // wf: [0..3]=Wih0(i*2+nt) [4..11]=Whh0 [12..19]=Wih1 [20..27]=Whh1
  short8 wf[28];
  {
    const int hi8 = (lane >> 4) << 3;
#pragma unroll
    for (int nt = 0; nt < 2; ++nt) {
      const int n = nt * 16 + (lane & 15);
      const int row = ((n >> 3) << 10) + ng * 8 + (n & 7);
#pragma unroll
      for (int i = 0; i < 2; ++i)
        wf[i * 2 + nt] = pack8(Wih0 + row * DIN + (2 * wid + i) * 32 + hi8);
#pragma unroll
      for (int i = 0; i < 4; ++i) {
        const int k = (4 * wid + i) * 32 + hi8;
        wf[4 + i * 2 + nt]  = pack8(Whh0 + row * HID + k);
        wf[12 + i * 2 + nt] = pack8(Wih1 + row * HID + k);
        wf[20 + i * 2 + nt] = pack8(Whh1 + row * HID + k);
      }
    }
  }

  // ---------- per-thread epilogue state (threads 0..255 only) ----------
  const int j = tid & 7;
  const int bl = (tid >> 3) & 31;  // local batch row 0..31
  const int b = mg * 32 + bl;      // global batch row
  const int jg = ng * 8 + j;       // global h column
  const int m = bl >> 4;           // local Mtile 0..1
  const int r = bl & 15;           // row within tile
  const bool epi = (tid < 256);
  float bias0[4], bias1[4];
#pragma unroll
  for (int g = 0; g < 4; ++g) {
    bias0[g] = bih0[g * HID + jg] + bhh0[g * HID + jg];
    bias1[g] = bih1[g * HID + jg] + bhh1[g * HID + jg];
  }
  float c0 = 0.0f, c1 = 0.0f;
  // byte offset of h(b, jg) inside one parity buffer (frag-tile layout)
  const int hoff = ((b >> 4) * 32 + (jg >> 5)) * 1024 +
                   ((b & 15) + 16 * ((jg >> 3) & 3)) * 16 + (jg & 7) * 2;

  if (tid == 0) __hip_atomic_store(&gen_lds, 0u, __ATOMIC_RELAXED, __HIP_MEMORY_SCOPE_WORKGROUP);
  __syncthreads();

  // ---------- wavefront loop: interval s computes layer0(s) and layer1(s-1) ----------
  for (int s = 0; s <= T_STEPS; ++s) {
    const int p0 = s & 1;
    const bool doL0 = (s < T_STEPS);
    const bool doL1 = (s >= 1);
    const unsigned char* h0r = h0b + (p0 ^ 1) * HBUF;   // h0(s-1)  (zeros at s=0)
    const unsigned char* h1r = h1b + p0 * HBUF;         // h1(s-2)

    // x part first — no barrier dependency, overlaps the wait below
    f32x4 acc0[2][2];
    if (doL0) {
      const unsigned char* xs = xb + s * 65536;
#pragma unroll
      for (int mm = 0; mm < 2; ++mm) {
        acc0[mm][0] = (f32x4){0.f, 0.f, 0.f, 0.f};
        acc0[mm][1] = (f32x4){0.f, 0.f, 0.f, 0.f};
#pragma unroll
        for (int i = 0; i < 2; ++i) {
          short8 af = *(const short8*)(xs + (((mg * 2 + mm) * 16) + 2 * wid + i) * 1024 + lane16);
          acc0[mm][0] = MFMA(af, wf[i * 2 + 0], acc0[mm][0], 0, 0, 0);
          acc0[mm][1] = MFMA(af, wf[i * 2 + 1], acc0[mm][1], 0, 0, 0);
        }
      }
    }

    wait_gen(root, &gen_lds, (unsigned)s, tid);   // h0(s-1)/h1(s-2) at MALL

    // h part: block reads ONLY its 2 M-tiles; each h0 tile loaded once,
    // used for layer0 AND layer1. Accumulators flushed to LDS per-mm.
#pragma unroll
    for (int mm = 0; mm < 2; ++mm) {
      const int tbase = (mg * 2 + mm) * 32 + 4 * wid;
      short8 f0[4], f1[4];
#pragma unroll
      for (int i = 0; i < 4; ++i)
        f0[i] = ld_frag16(h0r, (tbase + i) * 1024 + lane16);
      if (doL1) {
#pragma unroll
        for (int i = 0; i < 4; ++i)
          f1[i] = ld_frag16(h1r, (tbase + i) * 1024 + lane16);
      }

      if (doL0) {
#pragma unroll
        for (int i = 0; i < 4; ++i) {
          acc0[mm][0] = MFMA(f0[i], wf[4 + i * 2 + 0], acc0[mm][0], 0, 0, 0);
          acc0[mm][1] = MFMA(f0[i], wf[4 + i * 2 + 1], acc0[mm][1], 0, 0, 0);
        }
        *(f32x4*)(&red[wid][mm][0][lane][0]) = acc0[mm][0];   // flush: acc0[mm] dead
        *(f32x4*)(&red[wid][mm][1][lane][0]) = acc0[mm][1];
      }
      if (doL1) {
        f32x4 a1n0 = {0.f, 0.f, 0.f, 0.f}, a1n1 = {0.f, 0.f, 0.f, 0.f};
#pragma unroll
        for (int i = 0; i < 4; ++i) {
          a1n0 = MFMA(f0[i], wf[12 + i * 2 + 0], a1n0, 0, 0, 0);
          a1n1 = MFMA(f0[i], wf[12 + i * 2 + 1], a1n1, 0, 0, 0);
        }
#pragma unroll
        for (int i = 0; i < 4; ++i) {
          a1n0 = MFMA(f1[i], wf[20 + i * 2 + 0], a1n0, 0, 0, 0);
          a1n1 = MFMA(f1[i], wf[20 + i * 2 + 1], a1n1, 0, 0, 0);
        }
        *(f32x4*)(&red2[wid][mm][0][lane][0]) = a1n0;   // flush: acc1 dead
        *(f32x4*)(&red2[wid][mm][1][lane][0]) = a1n1;
      }
    }
    __syncthreads();   // all partials in red/red2

    // ---------- layer0 reduce (8-way K-split) + epilogue ----------
    if (doL0 && epi) {
      float sg[4];
#pragma unroll
      for (int g = 0; g < 4; ++g) {
        const int n = g * 8 + j;
        const int nt = n >> 4;
        const int ln = ((r >> 2) << 4) | (n & 15);
        const int rg = r & 3;
        float t = bias0[g];
#pragma unroll
        for (int w2 = 0; w2 < 8; ++w2) t += red[w2][m][nt][ln][rg];
        sg[g] = t;
      }
      const float iv = sigf(sg[0]);
      const float fv = sigf(sg[1]);
      const float gv = tanh_(sg[2]);
      const float ov = sigf(sg[3]);
      c0 = fv * c0 + iv * gv;
      const float h0v = ov * tanh_(c0);
      // pack 2 adjacent columns' bf16 into one 4B bypass store (MALL-visible)
      unsigned hb = (unsigned)bf16r(h0v) & 0xFFFFu;
      unsigned nb = (unsigned)__shfl_down((int)hb, 1) & 0xFFFFu;
      if ((j & 1) == 0)
        __hip_atomic_store((unsigned*)(h0b + p0 * HBUF + hoff), hb | (nb << 16),
                           __ATOMIC_RELAXED, __HIP_MEMORY_SCOPE_AGENT);
    }
    // ---------- layer1 reduce + epilogue ----------
    float outv = 0.0f;
    if (doL1 && epi) {
      float sg[4];
#pragma unroll
      for (int g = 0; g < 4; ++g) {
        const int n = g * 8 + j;
        const int nt = n >> 4;
        const int ln = ((r >> 2) << 4) | (n & 15);
        const int rg = r & 3;
        float t = bias1[g];
#pragma unroll
        for (int w2 = 0; w2 < 8; ++w2) t += red2[w2][m][nt][ln][rg];
        sg[g] = t;
      }
      const float iv = sigf(sg[0]);
      const float fv = sigf(sg[1]);
      const float gv = tanh_(sg[2]);
      const float ov = sigf(sg[3]);
      c1 = fv * c1 + iv * gv;
      const float h1v = ov * tanh_(c1);
      outv = sigf(h1v);
      unsigned hb = (unsigned)bf16r(h1v) & 0xFFFFu;
      unsigned nb = (unsigned)__shfl_down((int)hb, 1) & 0xFFFFu;
      if ((j & 1) == 0)
        __hip_atomic_store((unsigned*)(h1b + (p0 ^ 1) * HBUF + hoff), hb | (nb << 16),
                           __ATOMIC_RELAXED, __HIP_MEMORY_SCOPE_AGENT);
    }

    // h stores acked at coherence point before block-wide signal
    asm volatile("s_waitcnt vmcnt(0)" ::: "memory");
    __syncthreads();   // red/red2 consumed, all waves' stores drained

    if (doL0 && tid == 0) {
      // 8 groups x 32 blocks
      unsigned v = __hip_atomic_fetch_add(&grp[(blk >> 5) * 32], 1u,
                                          __ATOMIC_RELAXED, __HIP_MEMORY_SCOPE_AGENT);
      if ((v & 31) == 31)
        __hip_atomic_fetch_add(root, 1u, __ATOMIC_RELAXED, __HIP_MEMORY_SCOPE_AGENT);
    }

    // out-store AFTER the signal — its HBM ack is off the critical chain
    if (doL1 && epi)
      __builtin_nontemporal_store(outv, &out[b * (T_STEPS * HID) + (s - 1) * HID + jg]);
  }
}

extern "C" void kernel_launch(void* const* d_in, const int* in_sizes, int n_in,
                              void* d_out, int out_size, void* d_ws, size_t ws_size,
                              hipStream_t stream) {
  const float* x    = (const float*)d_in[0];
  const float* Wih0 = (const float*)d_in[1];
  const float* Whh0 = (const float*)d_in[2];
  const float* bih0 = (const float*)d_in[3];
  const float* bhh0 = (const float*)d_in[4];
  const float* Wih1 = (const float*)d_in[5];
  const float* Whh1 = (const float*)d_in[6];
  const float* bih1 = (const float*)d_in[7];
  const float* bhh1 = (const float*)d_in[8];
  unsigned char* ws = (unsigned char*)d_ws;

  // zero barrier counters + h double-buffers (deterministic per call)
  (void)hipMemsetAsync(d_ws, 0, WS_XB, stream);
  hipLaunchKernelGGL(cast_x_kernel, dim3(1024), dim3(256), 0, stream, x, ws);
  hipLaunchKernelGGL(lstm_main, dim3(NBLOCKS), dim3(NTHREADS), 0, stream,
                     Wih0, Whh0, bih0, bhh0, Wih1, Whh1, bih1, bhh1,
                     (float*)d_out, ws);
}